// Round 1
// baseline (202.971 us; speedup 1.0000x reference)
//
#include <hip/hip_runtime.h>

// LengthRegulator: B=32, T=512, D=384, DUR_MAX=8, L = T*(DUR_MAX-1) = 3584
// out[b,f,:] = x[b, idx(f), :] for f < mel_len[b], else 0
// idx(f) = t such that cum[t-1] <= f < cum[t], cum = inclusive cumsum of max(dur,1)

#define T_DIM 512
#define D_DIM 384
#define VEC_PER_ROW (D_DIM / 4)   // 96 float4 per row

__global__ void __launch_bounds__(T_DIM)
lr_build_map(const int* __restrict__ dur, int* __restrict__ idx_map,
             float* __restrict__ mel_out, int L) {
    const int b = blockIdx.x;
    const int t = threadIdx.x;                 // 0..511
    __shared__ int s[T_DIM];

    int d = dur[b * T_DIM + t];
    int e = d > 1 ? d : 1;                     // eff in [1,7]
    s[t] = e;
    __syncthreads();

    // Hillis-Steele inclusive scan over 512 elements
    #pragma unroll
    for (int off = 1; off < T_DIM; off <<= 1) {
        int add = (t >= off) ? s[t - off] : 0;
        __syncthreads();
        s[t] += add;
        __syncthreads();
    }

    const int cum   = s[t];
    const int mel   = s[T_DIM - 1];
    const int start = cum - e;

    int* map_b = idx_map + (size_t)b * L;
    for (int k = 0; k < e; ++k)
        map_b[start + k] = t;

    // frames past mel_len -> sentinel (output zero)
    for (int f = mel + t; f < L; f += T_DIM)
        map_b[f] = -1;

    if (t == 0)
        mel_out[b] = (float)mel;
}

__global__ void __launch_bounds__(256)
lr_gather(const float4* __restrict__ x, const int* __restrict__ idx_map,
          float4* __restrict__ out, int L, int vec_per_batch) {
    const int b = blockIdx.y;
    const int g = blockIdx.x * 256 + threadIdx.x;    // vec index within batch
    if (g >= vec_per_batch) return;

    const int f = g / VEC_PER_ROW;                   // frame (const-divisor)
    const int w = g - f * VEC_PER_ROW;               // float4 within row

    const int idx = idx_map[(size_t)b * L + f];
    float4 v = make_float4(0.f, 0.f, 0.f, 0.f);
    if (idx >= 0)
        v = x[((size_t)b * T_DIM + idx) * VEC_PER_ROW + w];
    out[((size_t)b * L + (size_t)f) * VEC_PER_ROW + w] = v;
}

extern "C" void kernel_launch(void* const* d_in, const int* in_sizes, int n_in,
                              void* d_out, int out_size, void* d_ws, size_t ws_size,
                              hipStream_t stream) {
    const float* x   = (const float*)d_in[0];
    const int*   dur = (const int*)d_in[1];

    const int B = in_sizes[1] / T_DIM;               // 32
    const int L = (out_size - B) / (B * D_DIM);      // 3584

    int*   idx_map = (int*)d_ws;                     // B*L ints = 448 KiB
    float* out     = (float*)d_out;
    float* mel_out = out + (size_t)B * L * D_DIM;    // mel_len appended as f32

    lr_build_map<<<dim3(B), dim3(T_DIM), 0, stream>>>(dur, idx_map, mel_out, L);

    const int vec_per_batch = L * VEC_PER_ROW;       // 344064
    const int blocks = (vec_per_batch + 255) / 256;  // 1344
    lr_gather<<<dim3(blocks, B), dim3(256), 0, stream>>>(
        (const float4*)x, idx_map, (float4*)out, L, vec_per_batch);
}